// Round 4
// baseline (62.499 us; speedup 1.0000x reference)
//
#include <hip/hip_runtime.h>
#include <math.h>

#define TPB 256
#define WPB (TPB / 64)

// ---- kernel 1: per-block partials (write-before-read -> no ws init) ----
// Fast path (D=256, K=8): one 64-lane wave per sample; lane l holds
// scores[b][4l..4l+3] as one float4 (1 KiB/wave, ideal coalescing).
// idx + positive scores are wave-uniform -> scalar s_load broadcasts.
// The shape check uses host scalars only, so idx/scores loads issue
// SPECULATIVELY in parallel with the *ndev load (breaks the serial
// ndev -> idx -> pos-score dependent chain: 3 round trips -> 2).
__global__ __launch_bounds__(TPB) void mlrl_main(
        const float* __restrict__ scores,
        const int*   __restrict__ idx,
        const int*   __restrict__ ndev,
        int total_scores, int total_idx,
        float2* __restrict__ partials) {

    const int lane = threadIdx.x & 63;
    const int wv   = __builtin_amdgcn_readfirstlane((int)threadIdx.x) >> 6;
    const int gw      = blockIdx.x * WPB + wv;
    const int gstride = gridDim.x * WPB;

    float loss = 0.0f, pairs = 0.0f;

    // shape test from host scalars only (no device load needed)
    const bool shape_ok = ((total_scores & 255) == 0) &&
                          ((long long)total_idx * 32LL == (long long)total_scores);
    const int Bf = total_scores >> 8;     // B if D==256

    // --- speculative fast-path loads (always in-bounds; discarded if D!=256)
    int4 i0 = {}, i1 = {};
    float4 v = {};
    const bool spec = shape_ok && (gw < Bf);
    if (spec) {
        const int rb = gw << 8;
        const int ib = gw << 3;
        i0 = *reinterpret_cast<const int4*>(idx + ib);
        i1 = *reinterpret_cast<const int4*>(idx + ib + 4);
        v  = *reinterpret_cast<const float4*>(scores + rb + (lane << 2));
    }

    const int D = *ndev;                  // s_load, overlaps the loads above
    const bool fast = shape_ok && (D == 256);

    if (fast) {
        for (int b = gw; b < Bf; b += gstride) {
            const int rb = b << 8;
            if (b != gw) {                // grid-stride tail (not hit by bench)
                const int ib = b << 3;
                i0 = *reinterpret_cast<const int4*>(idx + ib);
                i1 = *reinterpret_cast<const int4*>(idx + ib + 4);
                v  = *reinterpret_cast<const float4*>(scores + rb + (lane << 2));
            }
            int ik[8] = { i0.x, i0.y, i0.z, i0.w, i1.x, i1.y, i1.z, i1.w };

            float c[8];                   // c[k] = 1 - s_pos[k], -inf if dup
            int P = 0;
            #pragma unroll
            for (int k = 0; k < 8; ++k) {
                bool dup = false;
                #pragma unroll
                for (int j = 0; j < 8; ++j)
                    if (j < k) dup |= (ik[j] == ik[k]);
                const float pscore = scores[rb + ik[k]];   // uniform s_load
                if (!dup) { ++P; c[k] = 1.0f - pscore; }
                else      { c[k] = -INFINITY; }
            }

            const int e0 = lane << 2;
            const float se[4] = { v.x, v.y, v.z, v.w };
            #pragma unroll
            for (int j = 0; j < 4; ++j) {
                const int e = e0 + j;
                bool pos = false;
                #pragma unroll
                for (int k = 0; k < 8; ++k) pos |= (ik[k] == e);
                const float s = pos ? -INFINITY : se[j];
                #pragma unroll
                for (int k = 0; k < 8; ++k)
                    loss += fmaxf(0.0f, s + c[k]);   // relu(s_n - s_p + margin)
            }
            if (lane == 0) pairs += (float)((256 - P) * P);
        }
    } else if (D > 0) {
        // Generic runtime-D/K fallback (not hit by the bench shape).
        const int B = total_scores / D;
        const int K = (B > 0) ? (total_idx / B) : 0;
        for (int b = gw; b < B; b += gstride) {
            const int rb = b * D, ib = b * K;
            int P = 0;
            for (int k = 0; k < K; ++k) {
                bool dup = false;
                for (int j = 0; j < k; ++j) dup |= (idx[ib + j] == idx[ib + k]);
                if (!dup) ++P;
            }
            for (int d = lane; d < D; d += 64) {
                const float s = scores[rb + d] + 1.0f;
                bool pos = false;
                for (int k = 0; k < K; ++k) pos |= (idx[ib + k] == d);
                if (!pos) {
                    for (int k = 0; k < K; ++k) {
                        bool dup = false;
                        for (int j = 0; j < k; ++j) dup |= (idx[ib + j] == idx[ib + k]);
                        if (!dup) {
                            const float t = s - scores[rb + idx[ib + k]];
                            loss += (t > 0.0f) ? t : 0.0f;
                        }
                    }
                }
            }
            if (lane == 0) pairs += (float)((D - P) * P);
        }
    }

    // wave reduce (loss only; pairs already lives on lane 0 of each wave)
    #pragma unroll
    for (int off = 32; off > 0; off >>= 1)
        loss += __shfl_down(loss, off, 64);

    __shared__ float2 red[WPB];
    if (lane == 0) red[wv] = make_float2(loss, pairs);
    __syncthreads();
    if (threadIdx.x == 0) {
        float2 acc = red[0];
        #pragma unroll
        for (int w = 1; w < WPB; ++w) { acc.x += red[w].x; acc.y += red[w].y; }
        partials[blockIdx.x] = acc;
    }
}

// ---- kernel 2: single-wave reduce of <=2048 partials, no LDS, no sync ----
__global__ __launch_bounds__(64) void mlrl_finalize(
        const float2* __restrict__ partials, int n, float* __restrict__ out) {
    const int lane = threadIdx.x & 63;
    double l = 0.0, p = 0.0;
    for (int i = lane; i < n; i += 64) {
        const float2 v = partials[i];
        l += (double)v.x;
        p += (double)v.y;
    }
    #pragma unroll
    for (int off = 32; off > 0; off >>= 1) {
        l += __shfl_down(l, off, 64);
        p += __shfl_down(p, off, 64);
    }
    if (lane == 0)
        out[0] = (p > 0.0) ? (float)(l / (p < 1.0 ? 1.0 : p)) : 0.0f;
}

extern "C" void kernel_launch(void* const* d_in, const int* in_sizes, int n_in,
                              void* d_out, int out_size, void* d_ws, size_t ws_size,
                              hipStream_t stream) {
    const float* scores = (const float*)d_in[0];
    const int*   idx    = (const int*)d_in[1];
    const int*   ndev   = (const int*)d_in[2];
    float*       out    = (float*)d_out;

    const int total_scores = in_sizes[0];  // B*D
    const int total_idx    = in_sizes[1];  // B*K

    // 4 waves/block, 1 sample/wave at D=256 -> 1024 score elems per block.
    int nblk = total_scores >> 10;
    if (nblk < 1)    nblk = 1;
    if (nblk > 2048) nblk = 2048;
    if ((size_t)nblk * sizeof(float2) > ws_size)
        nblk = (int)(ws_size / sizeof(float2));
    if (nblk < 1) nblk = 1;

    float2* partials = (float2*)d_ws;

    mlrl_main<<<nblk, TPB, 0, stream>>>(scores, idx, ndev,
                                        total_scores, total_idx, partials);
    mlrl_finalize<<<1, 64, 0, stream>>>(partials, nblk, out);
}